// Round 1
// baseline (604.911 us; speedup 1.0000x reference)
//
#include <hip/hip_runtime.h>
#include <math.h>

// SampleScoreModel fused flash kernel — fp32 in/out.
// R11: occupancy push. LDS 59392->54272 B (XOR chunk-swizzles replace pads:
// K chunk ^= row&7 at 512B row stride; V^T chunk ^= (row>>1)&3 at 64B stride;
// both derived bank-uniform, equivalent to the old pads) -> 3 blocks/CU.
// ns=12 ragged splits -> 768 blocks = exactly 3/CU. Plus: setprio around MFMA
// clusters, defer-max rescale (THR=12 log2), prep_t reads bf16 plane, t-dtype
// classify hoisted into prep (flag in ws).

typedef float  f32x4 __attribute__((ext_vector_type(4)));
typedef short  s16x8 __attribute__((ext_vector_type(8)));
typedef unsigned short u16;

#define LOG2E   1.44269504088896f
#define L2_10K  13.2877123795494f   /* log2(10000) */
#define L2_001 -6.64385618977472f   /* log2(0.01)  */
#define SMIN2   1e-8f               /* SIGMA_MIN^2 */
#define DDIM    256
#define DEFER_THR 12.0f             /* log2-domain defer-max threshold */

#if defined(__has_builtin)
#if __has_builtin(__builtin_amdgcn_exp2f)
#define EXP2(x) __builtin_amdgcn_exp2f(x)
#endif
#endif
#ifndef EXP2
#define EXP2(x) exp2f(x)
#endif

__device__ __forceinline__ u16 bf16_rne(float f) {
  unsigned int u = __builtin_bit_cast(unsigned int, f);
  u = (u + 0x7FFFu + ((u >> 16) & 1u)) >> 16;
  return (u16)u;
}
__device__ __forceinline__ float bf16_to_f(u16 h) {
  unsigned int u = ((unsigned int)h) << 16;
  return __builtin_bit_cast(float, u);
}
__device__ __forceinline__ float f16_to_f(u16 h) {
  int s = (h >> 15) & 1, e = (h >> 10) & 31, m = h & 1023;
  float v;
  if (e == 0)       v = ldexpf((float)m, -24);
  else if (e == 31) v = 3.0e38f;
  else              v = ldexpf((float)(1024 + m), e - 25);
  return s ? -v : v;
}

// t-dtype insurance (returns fp32-mode on genuine fp32 t~U[0,1)).
__device__ __forceinline__ int classify_t_dtype(const void* tp) {
  const u16*          u16p = (const u16*)tp;
  const unsigned int* u32p = (const unsigned int*)tp;
  int c16 = 0, c32 = 0;
  for (int i = 0; i < 128; ++i) {
    u16 u = u16p[i];
    int e = (u >> 7) & 0xFF;
    if (!(u & 0x8000) && e >= 113 && e <= 126) c16++;
  }
  for (int i = 0; i < 64; ++i) {
    unsigned int w = u32p[i];
    int e = (int)((w >> 23) & 0xFF);
    if (!(w & 0x80000000u) && e >= 113 && e <= 126) c32++;
  }
  if (c32 >= 51) return (c16 >= 102) ? 0 : 1;   // 0=bf16, 1=fp32
  return 2;                                      // 2=fp16
}
__device__ __forceinline__ float load_t(const void* tp, int i, int mode) {
  float v;
  if (mode == 0)      v = bf16_to_f(((const u16*)tp)[i]);
  else if (mode == 1) v = ((const float*)tp)[i];
  else                v = f16_to_f(((const u16*)tp)[i]);
  return fminf(fmaxf(v, 0.f), 1.f);
}

// ---------------- precompute kernels ----------------

// Row-major bf16 hi/lo planes + 0.5*||s||^2. Wave per row; lane owns 4 elems.
// Also: thread (0,0) classifies t's dtype once into *tflag.
__global__ __launch_bounds__(256)
void prep_rows(const float* __restrict__ smp, const void* __restrict__ t,
               u16* __restrict__ gkhi, u16* __restrict__ gklo,
               float* __restrict__ gs2, int* __restrict__ tflag, int N)
{
  if (blockIdx.x == 0 && threadIdx.x == 0) *tflag = classify_t_dtype(t);
  int row  = blockIdx.x * 4 + (threadIdx.x >> 6);
  int lane = threadIdx.x & 63;
  float4 v4 = *(const float4*)(smp + (size_t)row * DDIM + lane * 4);
  float v[4] = {v4.x, v4.y, v4.z, v4.w};
  ushort4 h, l;
  u16 hh[4], ll[4];
  float s2 = 0.f;
#pragma unroll
  for (int e = 0; e < 4; ++e) {
    hh[e] = bf16_rne(v[e]);
    ll[e] = bf16_rne(v[e] - bf16_to_f(hh[e]));
    s2 = fmaf(v[e], v[e], s2);
  }
  h.x = hh[0]; h.y = hh[1]; h.z = hh[2]; h.w = hh[3];
  l.x = ll[0]; l.y = ll[1]; l.z = ll[2]; l.w = ll[3];
  *(ushort4*)(gkhi + (size_t)row * DDIM + lane * 4) = h;
  *(ushort4*)(gklo + (size_t)row * DDIM + lane * 4) = l;
#pragma unroll
  for (int msk = 1; msk <= 32; msk <<= 1) s2 += __shfl_xor(s2, msk);
  if (lane == 0) gs2[row] = 0.5f * s2;
}

// Tile-blocked transposed V (bf16 hi) built FROM the hi plane (u16 reads, half
// the traffic of re-reading fp32 smp, zero conversions).
// gvt[(n0/32)*256 + d][0..31] = bf16(V[n0+nn][d]).
__global__ __launch_bounds__(256)
void prep_t(const u16* __restrict__ gkhi, u16* __restrict__ gvt, int N)
{
  int d  = threadIdx.x;
  int n0 = blockIdx.x * 32;
  u16 buf[32];
#pragma unroll
  for (int i = 0; i < 32; ++i)
    buf[i] = gkhi[(size_t)(n0 + i) * DDIM + d];   // coalesced across threads
  u16* dst = gvt + ((size_t)blockIdx.x * 256 + d) * 32;
#pragma unroll
  for (int j = 0; j < 4; ++j)
    *(s16x8*)(dst + j * 8) = *(s16x8*)&buf[j * 8];
}

// ---------------- flash kernel ----------------

#define PSTR 40

// K planes: [32][256] ushorts, 16B chunks swizzled by (row&7)  -> 16384 B each
// V^T:      [256][32] ushorts, 16B chunks swizzled by (row>>1)&3 -> 16384 B
// P:        per-wave round-trip, PSTR=40 pad                    ->  5120 B
struct __align__(16) Smem {
  u16 khi[32 * 256];     // 16384 B
  u16 klo[32 * 256];     // 16384 B
  u16 vt [256 * 32];     // 16384 B
  u16 p  [4][16 * PSTR]; //  5120 B
};  // 54272 B -> 3 blocks/CU (163840/3 = 54613)

__global__ __launch_bounds__(256, 3)
void flash_kernel(const void* __restrict__ t, const float* __restrict__ x,
                  const u16* __restrict__ gkhi, const u16* __restrict__ gklo,
                  const u16* __restrict__ gvt, const float* __restrict__ gs2,
                  const int* __restrict__ tflag, float* __restrict__ out,
                  float* __restrict__ pO, float* __restrict__ pm,
                  float* __restrict__ pl, int B, int N)
{
  __shared__ Smem sm;
  const int tid  = threadIdx.x;
  const int wave = tid >> 6, lane = tid & 63;
  const int lq = lane >> 4, lr = lane & 15;      // quad, lane-in-quad
  const int m0 = blockIdx.x * 64 + wave * 16;    // wave owns 16 m-rows
  const int nsplit = gridDim.y, split = blockIdx.y;
  // ragged tile split: tiles_total = N/32 distributed as q+1 / q
  const int tiles_total = N >> 5;
  const int tq = tiles_total / nsplit, tr = tiles_total % nsplit;
  const int tile0 = split * tq + (split < tr ? split : tr);
  const int iters = tq + (split < tr ? 1 : 0);
  const int n0b = tile0 << 5;
  const int tmode = *tflag;

  float invd[4];
#pragma unroll
  for (int r = 0; r < 4; ++r) {
    int gm = m0 + lq * 4 + r;
    float tv = load_t(t, gm, tmode);
    float ts = EXP2(fmaf(tv, L2_10K, L2_001));
    invd[r] = LOG2E / (ts * ts + SMIN2);
  }

  // Q fragments (block-invariant): A-layout row = m0 + lr, k = ks*32 + lq*8 + j.
  s16x8 qhi[8], qlo[8];
  {
    const float* xr = x + (size_t)(m0 + lr) * DDIM;
#pragma unroll
    for (int ks = 0; ks < 8; ++ks) {
      const float4* p4 = (const float4*)(xr + ks * 32 + lq * 8);
      float4 a = p4[0], b = p4[1];
      float v[8] = {a.x, a.y, a.z, a.w, b.x, b.y, b.z, b.w};
#pragma unroll
      for (int j = 0; j < 8; ++j) {
        u16 h = bf16_rne(v[j]);
        u16 l = bf16_rne(v[j] - bf16_to_f(h));
        qhi[ks][j] = (short)h;
        qlo[ks][j] = (short)l;
      }
    }
  }

  f32x4 O[16];
#pragma unroll
  for (int dt = 0; dt < 16; ++dt) O[dt] = (f32x4){0.f, 0.f, 0.f, 0.f};
  float mrun[4], lrun[4];
#pragma unroll
  for (int r = 0; r < 4; ++r) { mrun[r] = -1e30f; lrun[r] = 0.f; }

  // staging indices (fixed per thread)
  const int sr = tid & 31, scc = tid >> 5;       // khi/klo: row, 32-col chunk
  const int ksw  = sr & 7;                       // K write swizzle key
  const int vsw  = (tid >> 1) & 3;               // vt write swizzle key
  const int krsw = lr & 7;                       // K read swizzle key (row&7)

  // prefetch registers: 4x khi, 4x klo, 4x vt (16B each)
  s16x8 pk[4], plr[4], pv[4];
  float s2a, s2b;

  {  // issue tile 0
    const s16x8* kb = (const s16x8*)(gkhi + (size_t)(n0b + sr) * DDIM + scc * 32);
    const s16x8* lb = (const s16x8*)(gklo + (size_t)(n0b + sr) * DDIM + scc * 32);
    const s16x8* vb = (const s16x8*)(gvt + ((size_t)(n0b >> 5) * 256 + tid) * 32);
#pragma unroll
    for (int j = 0; j < 4; ++j) { pk[j] = kb[j]; plr[j] = lb[j]; pv[j] = vb[j]; }
    s2a = gs2[n0b + lr]; s2b = gs2[n0b + 16 + lr];
  }

  int n0 = n0b;
  for (int it = 0; it < iters; ++it) {
    __syncthreads();   // previous tile fully consumed

    // ---- commit prefetched tile to LDS (vector writes; XOR chunk swizzles) ----
#pragma unroll
    for (int j = 0; j < 4; ++j) {
      int kc = (((scc << 2) + j) ^ ksw) << 3;    // swizzled ushort col in K row
      *(s16x8*)&sm.khi[sr * 256 + kc] = pk[j];
      *(s16x8*)&sm.klo[sr * 256 + kc] = plr[j];
      *(s16x8*)&sm.vt [(tid << 5) + ((j ^ vsw) << 3)] = pv[j];
    }
    float cs2a = s2a, cs2b = s2b;
    __syncthreads();

    // ---- kick prefetch for next tile (drains during compute below) ----
    if (it + 1 < iters) {
      int nn = n0 + 32;
      const s16x8* kb = (const s16x8*)(gkhi + (size_t)(nn + sr) * DDIM + scc * 32);
      const s16x8* lb = (const s16x8*)(gklo + (size_t)(nn + sr) * DDIM + scc * 32);
      const s16x8* vb = (const s16x8*)(gvt + ((size_t)(nn >> 5) * 256 + tid) * 32);
#pragma unroll
      for (int j = 0; j < 4; ++j) { pk[j] = kb[j]; plr[j] = lb[j]; pv[j] = vb[j]; }
      s2a = gs2[nn + lr]; s2b = gs2[nn + 16 + lr];
    }

    // ---- QK^T (3-pass split bf16); acc init = -0.5*||s||^2 (from gs2) ----
    f32x4 acc[2];
    acc[0] = (f32x4){-cs2a, -cs2a, -cs2a, -cs2a};
    acc[1] = (f32x4){-cs2b, -cs2b, -cs2b, -cs2b};
    __builtin_amdgcn_s_setprio(1);
#pragma unroll
    for (int nt = 0; nt < 2; ++nt) {
#pragma unroll
      for (int ks = 0; ks < 8; ++ks) {
        int co = (((ks << 2) + lq) ^ krsw) << 3;
        const s16x8 bh = *(const s16x8*)&sm.khi[(nt * 16 + lr) * 256 + co];
        const s16x8 bl = *(const s16x8*)&sm.klo[(nt * 16 + lr) * 256 + co];
        acc[nt] = __builtin_amdgcn_mfma_f32_16x16x32_bf16(qhi[ks], bh, acc[nt], 0, 0, 0);
        acc[nt] = __builtin_amdgcn_mfma_f32_16x16x32_bf16(qlo[ks], bh, acc[nt], 0, 0, 0);
        acc[nt] = __builtin_amdgcn_mfma_f32_16x16x32_bf16(qhi[ks], bl, acc[nt], 0, 0, 0);
      }
    }
    __builtin_amdgcn_s_setprio(0);

    // ---- online softmax (defer-max) + P->LDS (wave-private) ----
#pragma unroll
    for (int r = 0; r < 4; ++r) {
      float L[2];
      L[0] = acc[0][r] * invd[r];
      L[1] = acc[1][r] * invd[r];
      float tmax = fmaxf(L[0], L[1]);
#pragma unroll
      for (int msk = 1; msk <= 8; msk <<= 1)
        tmax = fmaxf(tmax, __shfl_xor(tmax, msk));
      float mnew = mrun[r];
      // T13 defer-max: skip the rescale while the tile max stays within
      // 2^DEFER_THR of the running max (P then bounded by 4096 — safe in
      // bf16 storage and fp32 accumulation; scale cancels at normalize).
      if (!__all(tmax - mnew <= DEFER_THR)) {
        mnew = fmaxf(mnew, tmax);
        float alpha = EXP2(mrun[r] - mnew);
        mrun[r] = mnew;
        lrun[r] *= alpha;
#pragma unroll
        for (int dt = 0; dt < 16; ++dt) O[dt][r] *= alpha;
      }
      float ps = 0.f;
#pragma unroll
      for (int nt = 0; nt < 2; ++nt) {
        u16 pq = bf16_rne(EXP2(L[nt] - mnew));
        ps += bf16_to_f(pq);   // sum the QUANTIZED p: consistent with PV
        sm.p[wave][(lq * 4 + r) * PSTR + nt * 16 + lr] = pq;
      }
#pragma unroll
      for (int msk = 1; msk <= 8; msk <<= 1) ps += __shfl_xor(ps, msk);
      lrun[r] += ps;
    }

    // ---- PV: O += P @ V  (vt read undoes the chunk swizzle) ----
    {
      const s16x8 pa = *(const s16x8*)&sm.p[wave][lr * PSTR + lq * 8];
      __builtin_amdgcn_s_setprio(1);
#pragma unroll
      for (int dt = 0; dt < 16; ++dt) {
        int row = dt * 16 + lr;
        const s16x8 bv = *(const s16x8*)&sm.vt[(row << 5) + ((lq ^ ((row >> 1) & 3)) << 3)];
        O[dt] = __builtin_amdgcn_mfma_f32_16x16x32_bf16(pa, bv, O[dt], 0, 0, 0);
      }
      __builtin_amdgcn_s_setprio(0);
    }
    n0 += 32;
  }

  // ---- epilogue ----
  if (nsplit == 1) {
#pragma unroll
    for (int r = 0; r < 4; ++r) {
      int gm = m0 + lq * 4 + r;
      float tv = load_t(t, gm, tmode);
      float ts = EXP2(fmaf(tv, L2_10K, L2_001));
      float den = ts * ts + SMIN2;
      float sc = ts / den;
      float il = 1.f / lrun[r];
#pragma unroll
      for (int dt = 0; dt < 16; ++dt) {
        int d = dt * 16 + lr;
        out[(size_t)gm * DDIM + d] = sc * (O[dt][r] * il - x[(size_t)gm * DDIM + d]);
      }
    }
  } else {
    size_t obase = (size_t)split * B * DDIM;
#pragma unroll
    for (int r = 0; r < 4; ++r) {
      int gm = m0 + lq * 4 + r;
#pragma unroll
      for (int dt = 0; dt < 16; ++dt)
        pO[obase + (size_t)gm * DDIM + dt * 16 + lr] = O[dt][r];
      if (lr == 0) {
        pm[(size_t)split * B + gm] = mrun[r];
        pl[(size_t)split * B + gm] = lrun[r];
      }
    }
  }
}

// ---------------- combine (float4) ----------------
__global__ __launch_bounds__(256)
void combine_kernel(const void* __restrict__ t, const float* __restrict__ x,
                    const float* __restrict__ pO, const float* __restrict__ pm,
                    const float* __restrict__ pl, float* __restrict__ out,
                    const int* __restrict__ tflag, int nsplit, int B)
{
  int idx = blockIdx.x * 256 + threadIdx.x;   // over B*64 float4s
  int b = idx >> 6;
  const int tmode = *tflag;
  float M = -1e30f;
  for (int s = 0; s < nsplit; ++s) M = fmaxf(M, pm[(size_t)s * B + b]);
  float4 num = {0.f, 0.f, 0.f, 0.f};
  float den = 0.f;
  for (int s = 0; s < nsplit; ++s) {
    float w = EXP2(pm[(size_t)s * B + b] - M);
    float4 po = ((const float4*)pO)[(size_t)s * B * 64 + idx];
    num.x += w * po.x; num.y += w * po.y; num.z += w * po.z; num.w += w * po.w;
    den += w * pl[(size_t)s * B + b];
  }
  float il = 1.f / den;
  float tv = load_t(t, b, tmode);
  float ts = EXP2(fmaf(tv, L2_10K, L2_001));
  float sc = ts / (ts * ts + SMIN2);
  float4 xx = ((const float4*)x)[idx];
  float4 o;
  o.x = sc * (num.x * il - xx.x);
  o.y = sc * (num.y * il - xx.y);
  o.z = sc * (num.z * il - xx.z);
  o.w = sc * (num.w * il - xx.w);
  ((float4*)out)[idx] = o;
}

extern "C" void kernel_launch(void* const* d_in, const int* in_sizes, int n_in,
                              void* d_out, int out_size, void* d_ws, size_t ws_size,
                              hipStream_t stream) {
  // Identify inputs BY SIZE: x has out_size elements, samples largest, t smallest.
  int xi = 0, si = 0, ti = 0;
  for (int i = 0; i < 3; ++i) {
    if (in_sizes[i] == out_size) xi = i;
    if (in_sizes[i] > in_sizes[si]) si = i;
    if (in_sizes[i] < in_sizes[ti]) ti = i;
  }
  const void*  t   = d_in[ti];                  // fp32 [B]
  const float* x   = (const float*)d_in[xi];    // fp32 [B,256]
  const float* smp = (const float*)d_in[si];    // fp32 [N,256]
  float* out = (float*)d_out;                   // fp32 [B,256]
  int B = out_size / DDIM;          // 4096
  int N = in_sizes[si] / DDIM;      // 8192

  // ws layout: gkhi | gklo | gvt | gs2 | tflag(+pad to 16B) | pO | pm | pl
  size_t plane = (size_t)N * DDIM;              // elements per u16 plane
  u16*   gkhi = (u16*)d_ws;
  u16*   gklo = gkhi + plane;
  u16*   gvt  = gklo + plane;
  float* gs2  = (float*)(gvt + plane);
  int*   tflag = (int*)(gs2 + N);
  float* pO   = gs2 + N + 4;                    // keep 16B alignment for float4
  size_t fixed = plane * 6 + (size_t)N * 4 + 16;  // bytes
  size_t per = (size_t)B * DDIM * sizeof(float) + (size_t)B * 2 * sizeof(float);
  // ns=12 -> 768 blocks = exactly 3 blocks/CU at 54272 B LDS.
  const int cand[6] = {12, 8, 6, 4, 2, 1};
  int ns = 1;
  for (int i = 0; i < 6; ++i)
    if (fixed + (size_t)cand[i] * per <= ws_size) { ns = cand[i]; break; }
  float* pm = pO + (size_t)ns * B * DDIM;
  float* pl = pm + (size_t)ns * B;

  prep_rows<<<dim3(N / 4), 256, 0, stream>>>(smp, t, gkhi, gklo, gs2, tflag, N);
  prep_t<<<dim3(N / 32), 256, 0, stream>>>(gkhi, gvt, N);
  flash_kernel<<<dim3(B / 64, ns), 256, 0, stream>>>(t, x, gkhi, gklo, gvt, gs2, tflag,
                                                     out, pO, pm, pl, B, N);
  if (ns > 1)
    combine_kernel<<<dim3(B * 64 / 256), 256, 0, stream>>>(t, x, pO, pm, pl, out, tflag, ns, B);
}

// Round 2
// 261.861 us; speedup vs baseline: 2.3100x; 2.3100x over previous
//
#include <hip/hip_runtime.h>
#include <math.h>

// SampleScoreModel fused flash kernel — fp32 in/out.
// R12: R11 minus the launch-bounds regression. R11's __launch_bounds__(256,3)
// squeezed VGPRs 128->84 -> massive scratch spill (FETCH 549MB, WRITE 872MB,
// 592us). Keep LDS at 54272B (3 blocks/CU LDS-wise) but use (256,2) which
// R10-verified gives exactly 128 VGPR, zero spill; 128 VGPR allows 4 waves/SIMD
// so HW reaches the LDS-limited 3 blocks/CU without an allocator cap.
// Kept from R11: XOR chunk-swizzles (conflicts 1.29e7->8.65e6), ns=12 ragged
// splits (768 blocks = 3/CU), setprio around MFMA, defer-max (THR=12 log2),
// prep_t reads bf16 plane, t-dtype classify hoisted into prep.

typedef float  f32x4 __attribute__((ext_vector_type(4)));
typedef short  s16x8 __attribute__((ext_vector_type(8)));
typedef unsigned short u16;

#define LOG2E   1.44269504088896f
#define L2_10K  13.2877123795494f   /* log2(10000) */
#define L2_001 -6.64385618977472f   /* log2(0.01)  */
#define SMIN2   1e-8f               /* SIGMA_MIN^2 */
#define DDIM    256
#define DEFER_THR 12.0f             /* log2-domain defer-max threshold */

#if defined(__has_builtin)
#if __has_builtin(__builtin_amdgcn_exp2f)
#define EXP2(x) __builtin_amdgcn_exp2f(x)
#endif
#endif
#ifndef EXP2
#define EXP2(x) exp2f(x)
#endif

__device__ __forceinline__ u16 bf16_rne(float f) {
  unsigned int u = __builtin_bit_cast(unsigned int, f);
  u = (u + 0x7FFFu + ((u >> 16) & 1u)) >> 16;
  return (u16)u;
}
__device__ __forceinline__ float bf16_to_f(u16 h) {
  unsigned int u = ((unsigned int)h) << 16;
  return __builtin_bit_cast(float, u);
}
__device__ __forceinline__ float f16_to_f(u16 h) {
  int s = (h >> 15) & 1, e = (h >> 10) & 31, m = h & 1023;
  float v;
  if (e == 0)       v = ldexpf((float)m, -24);
  else if (e == 31) v = 3.0e38f;
  else              v = ldexpf((float)(1024 + m), e - 25);
  return s ? -v : v;
}

// t-dtype insurance (returns fp32-mode on genuine fp32 t~U[0,1)).
__device__ __forceinline__ int classify_t_dtype(const void* tp) {
  const u16*          u16p = (const u16*)tp;
  const unsigned int* u32p = (const unsigned int*)tp;
  int c16 = 0, c32 = 0;
  for (int i = 0; i < 128; ++i) {
    u16 u = u16p[i];
    int e = (u >> 7) & 0xFF;
    if (!(u & 0x8000) && e >= 113 && e <= 126) c16++;
  }
  for (int i = 0; i < 64; ++i) {
    unsigned int w = u32p[i];
    int e = (int)((w >> 23) & 0xFF);
    if (!(w & 0x80000000u) && e >= 113 && e <= 126) c32++;
  }
  if (c32 >= 51) return (c16 >= 102) ? 0 : 1;   // 0=bf16, 1=fp32
  return 2;                                      // 2=fp16
}
__device__ __forceinline__ float load_t(const void* tp, int i, int mode) {
  float v;
  if (mode == 0)      v = bf16_to_f(((const u16*)tp)[i]);
  else if (mode == 1) v = ((const float*)tp)[i];
  else                v = f16_to_f(((const u16*)tp)[i]);
  return fminf(fmaxf(v, 0.f), 1.f);
}

// ---------------- precompute kernels ----------------

// Row-major bf16 hi/lo planes + 0.5*||s||^2. Wave per row; lane owns 4 elems.
// Also: thread (0,0) classifies t's dtype once into *tflag.
__global__ __launch_bounds__(256)
void prep_rows(const float* __restrict__ smp, const void* __restrict__ t,
               u16* __restrict__ gkhi, u16* __restrict__ gklo,
               float* __restrict__ gs2, int* __restrict__ tflag, int N)
{
  if (blockIdx.x == 0 && threadIdx.x == 0) *tflag = classify_t_dtype(t);
  int row  = blockIdx.x * 4 + (threadIdx.x >> 6);
  int lane = threadIdx.x & 63;
  float4 v4 = *(const float4*)(smp + (size_t)row * DDIM + lane * 4);
  float v[4] = {v4.x, v4.y, v4.z, v4.w};
  ushort4 h, l;
  u16 hh[4], ll[4];
  float s2 = 0.f;
#pragma unroll
  for (int e = 0; e < 4; ++e) {
    hh[e] = bf16_rne(v[e]);
    ll[e] = bf16_rne(v[e] - bf16_to_f(hh[e]));
    s2 = fmaf(v[e], v[e], s2);
  }
  h.x = hh[0]; h.y = hh[1]; h.z = hh[2]; h.w = hh[3];
  l.x = ll[0]; l.y = ll[1]; l.z = ll[2]; l.w = ll[3];
  *(ushort4*)(gkhi + (size_t)row * DDIM + lane * 4) = h;
  *(ushort4*)(gklo + (size_t)row * DDIM + lane * 4) = l;
#pragma unroll
  for (int msk = 1; msk <= 32; msk <<= 1) s2 += __shfl_xor(s2, msk);
  if (lane == 0) gs2[row] = 0.5f * s2;
}

// Tile-blocked transposed V (bf16 hi) built FROM the hi plane (u16 reads, half
// the traffic of re-reading fp32 smp, zero conversions).
// gvt[(n0/32)*256 + d][0..31] = bf16(V[n0+nn][d]).
__global__ __launch_bounds__(256)
void prep_t(const u16* __restrict__ gkhi, u16* __restrict__ gvt, int N)
{
  int d  = threadIdx.x;
  int n0 = blockIdx.x * 32;
  u16 buf[32];
#pragma unroll
  for (int i = 0; i < 32; ++i)
    buf[i] = gkhi[(size_t)(n0 + i) * DDIM + d];   // coalesced across threads
  u16* dst = gvt + ((size_t)blockIdx.x * 256 + d) * 32;
#pragma unroll
  for (int j = 0; j < 4; ++j)
    *(s16x8*)(dst + j * 8) = *(s16x8*)&buf[j * 8];
}

// ---------------- flash kernel ----------------

#define PSTR 40

// K planes: [32][256] ushorts, 16B chunks swizzled by (row&7)  -> 16384 B each
// V^T:      [256][32] ushorts, 16B chunks swizzled by (row>>1)&3 -> 16384 B
// P:        per-wave round-trip, PSTR=40 pad                    ->  5120 B
struct __align__(16) Smem {
  u16 khi[32 * 256];     // 16384 B
  u16 klo[32 * 256];     // 16384 B
  u16 vt [256 * 32];     // 16384 B
  u16 p  [4][16 * PSTR]; //  5120 B
};  // 54272 B -> 3 blocks/CU (163840/3 = 54613)

__global__ __launch_bounds__(256, 2)   // (256,2): R10-verified 128 VGPR, no spill
void flash_kernel(const void* __restrict__ t, const float* __restrict__ x,
                  const u16* __restrict__ gkhi, const u16* __restrict__ gklo,
                  const u16* __restrict__ gvt, const float* __restrict__ gs2,
                  const int* __restrict__ tflag, float* __restrict__ out,
                  float* __restrict__ pO, float* __restrict__ pm,
                  float* __restrict__ pl, int B, int N)
{
  __shared__ Smem sm;
  const int tid  = threadIdx.x;
  const int wave = tid >> 6, lane = tid & 63;
  const int lq = lane >> 4, lr = lane & 15;      // quad, lane-in-quad
  const int m0 = blockIdx.x * 64 + wave * 16;    // wave owns 16 m-rows
  const int nsplit = gridDim.y, split = blockIdx.y;
  // ragged tile split: tiles_total = N/32 distributed as q+1 / q
  const int tiles_total = N >> 5;
  const int tq = tiles_total / nsplit, tr = tiles_total % nsplit;
  const int tile0 = split * tq + (split < tr ? split : tr);
  const int iters = tq + (split < tr ? 1 : 0);
  const int n0b = tile0 << 5;
  const int tmode = *tflag;

  float invd[4];
#pragma unroll
  for (int r = 0; r < 4; ++r) {
    int gm = m0 + lq * 4 + r;
    float tv = load_t(t, gm, tmode);
    float ts = EXP2(fmaf(tv, L2_10K, L2_001));
    invd[r] = LOG2E / (ts * ts + SMIN2);
  }

  // Q fragments (block-invariant): A-layout row = m0 + lr, k = ks*32 + lq*8 + j.
  s16x8 qhi[8], qlo[8];
  {
    const float* xr = x + (size_t)(m0 + lr) * DDIM;
#pragma unroll
    for (int ks = 0; ks < 8; ++ks) {
      const float4* p4 = (const float4*)(xr + ks * 32 + lq * 8);
      float4 a = p4[0], b = p4[1];
      float v[8] = {a.x, a.y, a.z, a.w, b.x, b.y, b.z, b.w};
#pragma unroll
      for (int j = 0; j < 8; ++j) {
        u16 h = bf16_rne(v[j]);
        u16 l = bf16_rne(v[j] - bf16_to_f(h));
        qhi[ks][j] = (short)h;
        qlo[ks][j] = (short)l;
      }
    }
  }

  f32x4 O[16];
#pragma unroll
  for (int dt = 0; dt < 16; ++dt) O[dt] = (f32x4){0.f, 0.f, 0.f, 0.f};
  float mrun[4], lrun[4];
#pragma unroll
  for (int r = 0; r < 4; ++r) { mrun[r] = -1e30f; lrun[r] = 0.f; }

  // staging indices (fixed per thread)
  const int sr = tid & 31, scc = tid >> 5;       // khi/klo: row, 32-col chunk
  const int ksw  = sr & 7;                       // K write swizzle key
  const int vsw  = (tid >> 1) & 3;               // vt write swizzle key
  const int krsw = lr & 7;                       // K read swizzle key (row&7)

  // prefetch registers: 4x khi, 4x klo, 4x vt (16B each)
  s16x8 pk[4], plr[4], pv[4];
  float s2a, s2b;

  {  // issue tile 0
    const s16x8* kb = (const s16x8*)(gkhi + (size_t)(n0b + sr) * DDIM + scc * 32);
    const s16x8* lb = (const s16x8*)(gklo + (size_t)(n0b + sr) * DDIM + scc * 32);
    const s16x8* vb = (const s16x8*)(gvt + ((size_t)(n0b >> 5) * 256 + tid) * 32);
#pragma unroll
    for (int j = 0; j < 4; ++j) { pk[j] = kb[j]; plr[j] = lb[j]; pv[j] = vb[j]; }
    s2a = gs2[n0b + lr]; s2b = gs2[n0b + 16 + lr];
  }

  int n0 = n0b;
  for (int it = 0; it < iters; ++it) {
    __syncthreads();   // previous tile fully consumed

    // ---- commit prefetched tile to LDS (vector writes; XOR chunk swizzles) ----
#pragma unroll
    for (int j = 0; j < 4; ++j) {
      int kc = (((scc << 2) + j) ^ ksw) << 3;    // swizzled ushort col in K row
      *(s16x8*)&sm.khi[sr * 256 + kc] = pk[j];
      *(s16x8*)&sm.klo[sr * 256 + kc] = plr[j];
      *(s16x8*)&sm.vt [(tid << 5) + ((j ^ vsw) << 3)] = pv[j];
    }
    float cs2a = s2a, cs2b = s2b;
    __syncthreads();

    // ---- kick prefetch for next tile (drains during compute below) ----
    if (it + 1 < iters) {
      int nn = n0 + 32;
      const s16x8* kb = (const s16x8*)(gkhi + (size_t)(nn + sr) * DDIM + scc * 32);
      const s16x8* lb = (const s16x8*)(gklo + (size_t)(nn + sr) * DDIM + scc * 32);
      const s16x8* vb = (const s16x8*)(gvt + ((size_t)(nn >> 5) * 256 + tid) * 32);
#pragma unroll
      for (int j = 0; j < 4; ++j) { pk[j] = kb[j]; plr[j] = lb[j]; pv[j] = vb[j]; }
      s2a = gs2[nn + lr]; s2b = gs2[nn + 16 + lr];
    }

    // ---- QK^T (3-pass split bf16); acc init = -0.5*||s||^2 (from gs2) ----
    f32x4 acc[2];
    acc[0] = (f32x4){-cs2a, -cs2a, -cs2a, -cs2a};
    acc[1] = (f32x4){-cs2b, -cs2b, -cs2b, -cs2b};
    __builtin_amdgcn_s_setprio(1);
#pragma unroll
    for (int nt = 0; nt < 2; ++nt) {
#pragma unroll
      for (int ks = 0; ks < 8; ++ks) {
        int co = (((ks << 2) + lq) ^ krsw) << 3;
        const s16x8 bh = *(const s16x8*)&sm.khi[(nt * 16 + lr) * 256 + co];
        const s16x8 bl = *(const s16x8*)&sm.klo[(nt * 16 + lr) * 256 + co];
        acc[nt] = __builtin_amdgcn_mfma_f32_16x16x32_bf16(qhi[ks], bh, acc[nt], 0, 0, 0);
        acc[nt] = __builtin_amdgcn_mfma_f32_16x16x32_bf16(qlo[ks], bh, acc[nt], 0, 0, 0);
        acc[nt] = __builtin_amdgcn_mfma_f32_16x16x32_bf16(qhi[ks], bl, acc[nt], 0, 0, 0);
      }
    }
    __builtin_amdgcn_s_setprio(0);

    // ---- online softmax (defer-max) + P->LDS (wave-private) ----
#pragma unroll
    for (int r = 0; r < 4; ++r) {
      float L[2];
      L[0] = acc[0][r] * invd[r];
      L[1] = acc[1][r] * invd[r];
      float tmax = fmaxf(L[0], L[1]);
#pragma unroll
      for (int msk = 1; msk <= 8; msk <<= 1)
        tmax = fmaxf(tmax, __shfl_xor(tmax, msk));
      float mnew = mrun[r];
      // T13 defer-max: skip the rescale while the tile max stays within
      // 2^DEFER_THR of the running max (P then bounded by 4096 — safe in
      // bf16 storage and fp32 accumulation; scale cancels at normalize).
      if (!__all(tmax - mnew <= DEFER_THR)) {
        mnew = fmaxf(mnew, tmax);
        float alpha = EXP2(mrun[r] - mnew);
        mrun[r] = mnew;
        lrun[r] *= alpha;
#pragma unroll
        for (int dt = 0; dt < 16; ++dt) O[dt][r] *= alpha;
      }
      float ps = 0.f;
#pragma unroll
      for (int nt = 0; nt < 2; ++nt) {
        u16 pq = bf16_rne(EXP2(L[nt] - mnew));
        ps += bf16_to_f(pq);   // sum the QUANTIZED p: consistent with PV
        sm.p[wave][(lq * 4 + r) * PSTR + nt * 16 + lr] = pq;
      }
#pragma unroll
      for (int msk = 1; msk <= 8; msk <<= 1) ps += __shfl_xor(ps, msk);
      lrun[r] += ps;
    }

    // ---- PV: O += P @ V  (vt read undoes the chunk swizzle) ----
    {
      const s16x8 pa = *(const s16x8*)&sm.p[wave][lr * PSTR + lq * 8];
      __builtin_amdgcn_s_setprio(1);
#pragma unroll
      for (int dt = 0; dt < 16; ++dt) {
        int row = dt * 16 + lr;
        const s16x8 bv = *(const s16x8*)&sm.vt[(row << 5) + ((lq ^ ((row >> 1) & 3)) << 3)];
        O[dt] = __builtin_amdgcn_mfma_f32_16x16x32_bf16(pa, bv, O[dt], 0, 0, 0);
      }
      __builtin_amdgcn_s_setprio(0);
    }
    n0 += 32;
  }

  // ---- epilogue ----
  if (nsplit == 1) {
#pragma unroll
    for (int r = 0; r < 4; ++r) {
      int gm = m0 + lq * 4 + r;
      float tv = load_t(t, gm, tmode);
      float ts = EXP2(fmaf(tv, L2_10K, L2_001));
      float den = ts * ts + SMIN2;
      float sc = ts / den;
      float il = 1.f / lrun[r];
#pragma unroll
      for (int dt = 0; dt < 16; ++dt) {
        int d = dt * 16 + lr;
        out[(size_t)gm * DDIM + d] = sc * (O[dt][r] * il - x[(size_t)gm * DDIM + d]);
      }
    }
  } else {
    size_t obase = (size_t)split * B * DDIM;
#pragma unroll
    for (int r = 0; r < 4; ++r) {
      int gm = m0 + lq * 4 + r;
#pragma unroll
      for (int dt = 0; dt < 16; ++dt)
        pO[obase + (size_t)gm * DDIM + dt * 16 + lr] = O[dt][r];
      if (lr == 0) {
        pm[(size_t)split * B + gm] = mrun[r];
        pl[(size_t)split * B + gm] = lrun[r];
      }
    }
  }
}

// ---------------- combine (float4) ----------------
__global__ __launch_bounds__(256)
void combine_kernel(const void* __restrict__ t, const float* __restrict__ x,
                    const float* __restrict__ pO, const float* __restrict__ pm,
                    const float* __restrict__ pl, float* __restrict__ out,
                    const int* __restrict__ tflag, int nsplit, int B)
{
  int idx = blockIdx.x * 256 + threadIdx.x;   // over B*64 float4s
  int b = idx >> 6;
  const int tmode = *tflag;
  float M = -1e30f;
  for (int s = 0; s < nsplit; ++s) M = fmaxf(M, pm[(size_t)s * B + b]);
  float4 num = {0.f, 0.f, 0.f, 0.f};
  float den = 0.f;
  for (int s = 0; s < nsplit; ++s) {
    float w = EXP2(pm[(size_t)s * B + b] - M);
    float4 po = ((const float4*)pO)[(size_t)s * B * 64 + idx];
    num.x += w * po.x; num.y += w * po.y; num.z += w * po.z; num.w += w * po.w;
    den += w * pl[(size_t)s * B + b];
  }
  float il = 1.f / den;
  float tv = load_t(t, b, tmode);
  float ts = EXP2(fmaf(tv, L2_10K, L2_001));
  float sc = ts / (ts * ts + SMIN2);
  float4 xx = ((const float4*)x)[idx];
  float4 o;
  o.x = sc * (num.x * il - xx.x);
  o.y = sc * (num.y * il - xx.y);
  o.z = sc * (num.z * il - xx.z);
  o.w = sc * (num.w * il - xx.w);
  ((float4*)out)[idx] = o;
}

extern "C" void kernel_launch(void* const* d_in, const int* in_sizes, int n_in,
                              void* d_out, int out_size, void* d_ws, size_t ws_size,
                              hipStream_t stream) {
  // Identify inputs BY SIZE: x has out_size elements, samples largest, t smallest.
  int xi = 0, si = 0, ti = 0;
  for (int i = 0; i < 3; ++i) {
    if (in_sizes[i] == out_size) xi = i;
    if (in_sizes[i] > in_sizes[si]) si = i;
    if (in_sizes[i] < in_sizes[ti]) ti = i;
  }
  const void*  t   = d_in[ti];                  // fp32 [B]
  const float* x   = (const float*)d_in[xi];    // fp32 [B,256]
  const float* smp = (const float*)d_in[si];    // fp32 [N,256]
  float* out = (float*)d_out;                   // fp32 [B,256]
  int B = out_size / DDIM;          // 4096
  int N = in_sizes[si] / DDIM;      // 8192

  // ws layout: gkhi | gklo | gvt | gs2 | tflag(+pad to 16B) | pO | pm | pl
  size_t plane = (size_t)N * DDIM;              // elements per u16 plane
  u16*   gkhi = (u16*)d_ws;
  u16*   gklo = gkhi + plane;
  u16*   gvt  = gklo + plane;
  float* gs2  = (float*)(gvt + plane);
  int*   tflag = (int*)(gs2 + N);
  float* pO   = gs2 + N + 4;                    // keep 16B alignment for float4
  size_t fixed = plane * 6 + (size_t)N * 4 + 16;  // bytes
  size_t per = (size_t)B * DDIM * sizeof(float) + (size_t)B * 2 * sizeof(float);
  // ns=12 -> 768 blocks = exactly 3 blocks/CU at 54272 B LDS.
  const int cand[6] = {12, 8, 6, 4, 2, 1};
  int ns = 1;
  for (int i = 0; i < 6; ++i)
    if (fixed + (size_t)cand[i] * per <= ws_size) { ns = cand[i]; break; }
  float* pm = pO + (size_t)ns * B * DDIM;
  float* pl = pm + (size_t)ns * B;

  prep_rows<<<dim3(N / 4), 256, 0, stream>>>(smp, t, gkhi, gklo, gs2, tflag, N);
  prep_t<<<dim3(N / 32), 256, 0, stream>>>(gkhi, gvt, N);
  flash_kernel<<<dim3(B / 64, ns), 256, 0, stream>>>(t, x, gkhi, gklo, gvt, gs2, tflag,
                                                     out, pO, pm, pl, B, N);
  if (ns > 1)
    combine_kernel<<<dim3(B * 64 / 256), 256, 0, stream>>>(t, x, pO, pm, pl, out, tflag, ns, B);
}